// Round 1
// baseline (417.680 us; speedup 1.0000x reference)
//
#include <hip/hip_runtime.h>

// R1: latency-bound fix — drop kt/kp LDS staging (score frags loaded direct from
// global, intra-wave lam via shuffles), 2 barriers/tile instead of 4, NCHK 16->32,
// register prefetch of next tile, out_kernel barrier-free single-tile blocks.

#define Sx 4096
#define HDx 64
#define NF 9
#define NHEAD 64
#define NCHK 32            // kv: s-chunks per head  -> grid 2048
#define SCK (Sx / NCHK)    // 128 tokens per kv block
#define NTK (SCK / 64)     // 2 tiles of 64 tokens
#define NCHO 64            // out: one 64-token tile per block -> grid 4096
#define LROW 72            // kd_s row stride (bf16 units); 144 B = 16B-aligned

typedef __attribute__((ext_vector_type(8))) short bf16x8;
typedef __attribute__((ext_vector_type(4))) float f32x4;

__device__ __forceinline__ unsigned short f2bf(float f) {
    union { float f; unsigned u; } x; x.f = f;
    unsigned r = x.u + 0x7fffu + ((x.u >> 16) & 1u);   // RNE
    return (unsigned short)(r >> 16);
}
__device__ __forceinline__ float bf2f(unsigned short b) {
    union { unsigned u; float f; } x; x.u = ((unsigned)b) << 16;
    return x.f;
}
__device__ __forceinline__ bf16x8 pack8(float4 a, float4 b) {
    bf16x8 r;
    r[0] = (short)f2bf(a.x); r[1] = (short)f2bf(a.y);
    r[2] = (short)f2bf(a.z); r[3] = (short)f2bf(a.w);
    r[4] = (short)f2bf(b.x); r[5] = (short)f2bf(b.y);
    r[6] = (short)f2bf(b.z); r[7] = (short)f2bf(b.w);
    return r;
}

// argmax over the 16-lane group (first-max-wins) -> lambda. lam9 is LDS.
__device__ __forceinline__ float route_lam(float v, int l15, const float* lam9) {
    int idx = l15;
#pragma unroll
    for (int m = 1; m < 16; m <<= 1) {
        float ov = __shfl_xor(v, m, 16);
        int   oi = __shfl_xor(idx, m, 16);
        bool take = (ov > v) || (ov == v && oi < idx);
        v = take ? ov : v; idx = take ? oi : idx;
    }
    return lam9[idx];
}

// lane (l15,q) holds lam for rows q*4+r after route_lam; every lane needs the
// lam of its own DATA row l15. Intra-wave: 4 shuffles + 3 selects, no LDS/barrier.
__device__ __forceinline__ float lam_bcast(float r0, float r1, float r2, float r3, int l15) {
    const int src = ((l15 >> 2) << 4) + l15;   // a lane in group q' = l15>>2
    float t0 = __shfl(r0, src);
    float t1 = __shfl(r1, src);
    float t2 = __shfl(r2, src);
    float t3 = __shfl(r3, src);
    float lo = (l15 & 1) ? t1 : t0;
    float hi = (l15 & 1) ? t3 : t2;
    return (l15 & 2) ? hi : lo;
}

// ---------------------------------------------------------------------------
// Kernel 1: KVt[head][e][d] += sum_s (Kt - lam*Kp)[s,d] * V[s,e]
// Score frags loaded direct from global in MFMA A-layout (no kt/kp staging).
// Only kd_s (transposed K_diff) goes through LDS. 2 barriers per 64-token tile.
// ---------------------------------------------------------------------------
__global__ __launch_bounds__(256, 4) void kv_kernel(
    const float* __restrict__ Kt, const float* __restrict__ Kp,
    const float* __restrict__ V,  const float* __restrict__ lambdas,
    const float* __restrict__ Wk, float* __restrict__ KVt)
{
    __shared__ __align__(16) unsigned short kd_s[64][LROW];   // [d][s]
    __shared__ float lam9[16];

    const int tid  = threadIdx.x;
    const int lane = tid & 63;
    const int wave = tid >> 6;
    const int l15  = lane & 15;
    const int q    = lane >> 4;
    const int head  = blockIdx.x & (NHEAD - 1);
    const int chunk = blockIdx.x >> 6;           // 0..NCHK-1
    const size_t hbase = (size_t)head * Sx * HDx;
    const int sbase = chunk * SCK;
    const int myrow = wave * 16 + l15;           // token within 64-tile

    if (tid < NF) lam9[tid] = lambdas[tid];

    // Router-weight B-frags: B[k=cat-feat][n=router]; cols 9..15 zero.
    bf16x8 wb[4];
#pragma unroll
    for (int h = 0; h < 4; ++h)
#pragma unroll
        for (int j = 0; j < 8; ++j) {
            float w = (l15 < NF) ? Wk[l15 * 128 + h * 32 + q * 8 + j] : 0.f;
            wb[h][j] = (short)f2bf(w);
        }

    f32x4 acc[4];
#pragma unroll
    for (int mt = 0; mt < 4; ++mt) acc[mt] = (f32x4){0.f, 0.f, 0.f, 0.f};

    // ---- tile-0 loads, directly in frag layout ----
    const float* kt0 = Kt + hbase + (size_t)(sbase + myrow) * HDx + q * 8;
    const float* kp0 = Kp + hbase + (size_t)(sbase + myrow) * HDx + q * 8;
    float4 a0 = *(const float4*)(kt0),      a1 = *(const float4*)(kt0 + 4);
    float4 a2 = *(const float4*)(kt0 + 32), a3 = *(const float4*)(kt0 + 36);
    float4 b0 = *(const float4*)(kp0),      b1 = *(const float4*)(kp0 + 4);
    float4 b2 = *(const float4*)(kp0 + 32), b3 = *(const float4*)(kp0 + 36);
    float vv[16];
#pragma unroll
    for (int h = 0; h < 2; ++h)
#pragma unroll
        for (int j = 0; j < 8; ++j)
            vv[h * 8 + j] = V[hbase + (size_t)(sbase + h * 32 + q * 8 + j) * HDx + wave * 16 + l15];

    __syncthreads();   // lam9 visible

    bf16x8 af[4];
    af[0] = pack8(a0, a1); af[1] = pack8(a2, a3);
    af[2] = pack8(b0, b1); af[3] = pack8(b2, b3);

#pragma unroll
    for (int t = 0; t < NTK; ++t) {
        // ---- scores via MFMA ----
        f32x4 sc = (f32x4){0.f, 0.f, 0.f, 0.f};
#pragma unroll
        for (int h = 0; h < 4; ++h)
            sc = __builtin_amdgcn_mfma_f32_16x16x32_bf16(af[h], wb[h], sc, 0, 0, 0);
        float lr0 = route_lam((l15 < NF) ? sc[0] : -3.4e38f, l15, lam9);
        float lr1 = route_lam((l15 < NF) ? sc[1] : -3.4e38f, l15, lam9);
        float lr2 = route_lam((l15 < NF) ? sc[2] : -3.4e38f, l15, lam9);
        float lr3 = route_lam((l15 < NF) ? sc[3] : -3.4e38f, l15, lam9);
        const float lam = lam_bcast(lr0, lr1, lr2, lr3, l15);

        // ---- K_diff, written transposed [d][s] ----
#pragma unroll
        for (int h = 0; h < 2; ++h)
#pragma unroll
            for (int j = 0; j < 8; ++j)
                kd_s[h * 32 + q * 8 + j][myrow] =
                    f2bf(bf2f((unsigned short)af[h][j]) - lam * bf2f((unsigned short)af[2 + h][j]));

        // ---- prefetch next tile (overlaps barrier + MFMA phase) ----
        float4 na0, na1, na2, na3, nb0, nb1, nb2, nb3;
        float nvv[16];
        if (t + 1 < NTK) {
            const int s0n = sbase + (t + 1) * 64;
            const float* ktn = Kt + hbase + (size_t)(s0n + myrow) * HDx + q * 8;
            const float* kpn = Kp + hbase + (size_t)(s0n + myrow) * HDx + q * 8;
            na0 = *(const float4*)(ktn);      na1 = *(const float4*)(ktn + 4);
            na2 = *(const float4*)(ktn + 32); na3 = *(const float4*)(ktn + 36);
            nb0 = *(const float4*)(kpn);      nb1 = *(const float4*)(kpn + 4);
            nb2 = *(const float4*)(kpn + 32); nb3 = *(const float4*)(kpn + 36);
#pragma unroll
            for (int h = 0; h < 2; ++h)
#pragma unroll
                for (int j = 0; j < 8; ++j)
                    nvv[h * 8 + j] = V[hbase + (size_t)(s0n + h * 32 + q * 8 + j) * HDx + wave * 16 + l15];
        }

        // V B-frags for this tile
        bf16x8 bv[2];
#pragma unroll
        for (int h = 0; h < 2; ++h)
#pragma unroll
            for (int j = 0; j < 8; ++j) bv[h][j] = (short)f2bf(vv[h * 8 + j]);

        __syncthreads();   // kd_s writes visible

        // ---- KV MFMA ----
#pragma unroll
        for (int h = 0; h < 2; ++h)
#pragma unroll
            for (int mt = 0; mt < 4; ++mt) {
                bf16x8 ad = *(const bf16x8*)&kd_s[mt * 16 + l15][h * 32 + q * 8];
                acc[mt] = __builtin_amdgcn_mfma_f32_16x16x32_bf16(ad, bv[h], acc[mt], 0, 0, 0);
            }

        if (t + 1 < NTK) {
            __syncthreads();   // kd_s reads done before next tile overwrites
            af[0] = pack8(na0, na1); af[1] = pack8(na2, na3);
            af[2] = pack8(nb0, nb1); af[3] = pack8(nb2, nb3);
#pragma unroll
            for (int j = 0; j < 16; ++j) vv[j] = nvv[j];
        }
    }

    // ---- epilogue: atomic accumulate into transposed KVt[e][d] ----
    float* kvh = KVt + head * (HDx * HDx);
#pragma unroll
    for (int mt = 0; mt < 4; ++mt)
#pragma unroll
        for (int r = 0; r < 4; ++r) {
            const int d = mt * 16 + q * 4 + r;
            const int e = wave * 16 + l15;
            atomicAdd(&kvh[e * 64 + d], acc[mt][r]);
        }
}

// ---------------------------------------------------------------------------
// Kernel 2: O[s,e] = sum_d (Qt - lam*Qp)[s,d] * KV[d,e]
// Barrier-free streaming: one 64-token tile per block, Q loaded direct in frag
// layout, KV B-frags from L2. Only barrier is the lam9 publish.
// ---------------------------------------------------------------------------
__global__ __launch_bounds__(256, 4) void out_kernel(
    const float* __restrict__ Qt, const float* __restrict__ Qp,
    const float* __restrict__ lambdas, const float* __restrict__ Wq,
    const float* __restrict__ KVt, float* __restrict__ O)
{
    __shared__ float lam9[16];

    const int tid  = threadIdx.x;
    const int lane = tid & 63;
    const int wave = tid >> 6;
    const int l15  = lane & 15;
    const int q    = lane >> 4;
    const int head  = blockIdx.x & (NHEAD - 1);
    const int chunk = blockIdx.x >> 6;           // 0..NCHO-1
    const size_t hbase = (size_t)head * Sx * HDx;
    const int s0 = chunk * 64;
    const int myrow = wave * 16 + l15;

    if (tid < NF) lam9[tid] = lambdas[tid];

    // Q loads first (HBM, longest latency) — frag layout, coalesced 64B clusters
    const float* qt0 = Qt + hbase + (size_t)(s0 + myrow) * HDx + q * 8;
    const float* qp0 = Qp + hbase + (size_t)(s0 + myrow) * HDx + q * 8;
    float4 a0 = *(const float4*)(qt0),      a1 = *(const float4*)(qt0 + 4);
    float4 a2 = *(const float4*)(qt0 + 32), a3 = *(const float4*)(qt0 + 36);
    float4 b0 = *(const float4*)(qp0),      b1 = *(const float4*)(qp0 + 4);
    float4 b2 = *(const float4*)(qp0 + 32), b3 = *(const float4*)(qp0 + 36);

    bf16x8 wb[4];
#pragma unroll
    for (int h = 0; h < 4; ++h)
#pragma unroll
        for (int j = 0; j < 8; ++j) {
            float w = (l15 < NF) ? Wq[l15 * 128 + h * 32 + q * 8 + j] : 0.f;
            wb[h][j] = (short)f2bf(w);
        }

    // KV B-frags: B[k=d][n=e] from KVt[e][d] (L2-resident, 16 KB/head)
    bf16x8 bkv[4][2];
    const float* kvh = KVt + head * (HDx * HDx);
#pragma unroll
    for (int nt = 0; nt < 4; ++nt)
#pragma unroll
        for (int h = 0; h < 2; ++h) {
            const float* p = &kvh[(nt * 16 + l15) * 64 + h * 32 + q * 8];
            bkv[nt][h] = pack8(*(const float4*)p, *(const float4*)(p + 4));
        }

    __syncthreads();   // lam9 visible

    bf16x8 af[4];
    af[0] = pack8(a0, a1); af[1] = pack8(a2, a3);
    af[2] = pack8(b0, b1); af[3] = pack8(b2, b3);

    f32x4 sc = (f32x4){0.f, 0.f, 0.f, 0.f};
#pragma unroll
    for (int h = 0; h < 4; ++h)
        sc = __builtin_amdgcn_mfma_f32_16x16x32_bf16(af[h], wb[h], sc, 0, 0, 0);
    float lr0 = route_lam((l15 < NF) ? sc[0] : -3.4e38f, l15, lam9);
    float lr1 = route_lam((l15 < NF) ? sc[1] : -3.4e38f, l15, lam9);
    float lr2 = route_lam((l15 < NF) ? sc[2] : -3.4e38f, l15, lam9);
    float lr3 = route_lam((l15 < NF) ? sc[3] : -3.4e38f, l15, lam9);
    const float lam = lam_bcast(lr0, lr1, lr2, lr3, l15);

    // Q_diff A-frags (reuse score frags — same lane mapping)
    bf16x8 ad[2];
#pragma unroll
    for (int h = 0; h < 2; ++h)
#pragma unroll
        for (int j = 0; j < 8; ++j)
            ad[h][j] = (short)f2bf(bf2f((unsigned short)af[h][j])
                                   - lam * bf2f((unsigned short)af[2 + h][j]));

    f32x4 oacc[4];
#pragma unroll
    for (int nt = 0; nt < 4; ++nt) oacc[nt] = (f32x4){0.f, 0.f, 0.f, 0.f};
#pragma unroll
    for (int h = 0; h < 2; ++h)
#pragma unroll
        for (int nt = 0; nt < 4; ++nt)
            oacc[nt] = __builtin_amdgcn_mfma_f32_16x16x32_bf16(ad[h], bkv[nt][h], oacc[nt], 0, 0, 0);

#pragma unroll
    for (int nt = 0; nt < 4; ++nt)
#pragma unroll
        for (int r = 0; r < 4; ++r) {
            const int row = s0 + wave * 16 + q * 4 + r;
            O[hbase + (size_t)row * HDx + nt * 16 + l15] = oacc[nt][r];
        }
}

// ---------------------------------------------------------------------------
extern "C" void kernel_launch(void* const* d_in, const int* in_sizes, int n_in,
                              void* d_out, int out_size, void* d_ws, size_t ws_size,
                              hipStream_t stream) {
    const float* Qt      = (const float*)d_in[0];
    const float* Qp      = (const float*)d_in[1];
    const float* Kt      = (const float*)d_in[2];
    const float* Kp      = (const float*)d_in[3];
    const float* V       = (const float*)d_in[4];
    const float* lambdas = (const float*)d_in[5];
    const float* Wq      = (const float*)d_in[6];
    const float* Wk      = (const float*)d_in[7];
    float* O  = (float*)d_out;
    float* KV = (float*)d_ws;   // 64 heads * 64 * 64 fp32 = 1 MB (KVt: [e][d])

    hipMemsetAsync(d_ws, 0, (size_t)NHEAD * HDx * HDx * sizeof(float), stream);
    kv_kernel <<<NHEAD * NCHK, 256, 0, stream>>>(Kt, Kp, V, lambdas, Wk, KV);
    out_kernel<<<NHEAD * NCHO, 256, 0, stream>>>(Qt, Qp, lambdas, Wq, KV, O);
}

// Round 2
// 374.442 us; speedup vs baseline: 1.1155x; 1.1155x over previous
//
#include <hip/hip_runtime.h>

// R2: kill the atomic storm. kv blocks write private f32 partials (coalesced
// stores, no memset); kv_reduce sums partials -> bf16 KV in [e][d] frag order;
// out preloads KV as raw ushort8. NCHK=32 / NCHO=32 for 8 blocks/CU occupancy.
// kd double-buffered -> 1 barrier/tile. Runtime ws_size-aware chunk selection
// with atomic fallback if workspace is tiny.

#define Sx 4096
#define HDx 64
#define NF 9
#define NHEAD 64
#define NCHO 32            // out: s-chunks per head -> grid 2048, 2 tiles/block
#define SCO (Sx / NCHO)
#define NTO (SCO / 64)
#define LROW 72            // kd_s row stride (bf16 units); 144 B = 16B-aligned

typedef __attribute__((ext_vector_type(8))) short bf16x8;
typedef __attribute__((ext_vector_type(4))) float f32x4;

__device__ __forceinline__ unsigned short f2bf(float f) {
    union { float f; unsigned u; } x; x.f = f;
    unsigned r = x.u + 0x7fffu + ((x.u >> 16) & 1u);   // RNE
    return (unsigned short)(r >> 16);
}
__device__ __forceinline__ float bf2f(unsigned short b) {
    union { unsigned u; float f; } x; x.u = ((unsigned)b) << 16;
    return x.f;
}
__device__ __forceinline__ bf16x8 pack8(float4 a, float4 b) {
    bf16x8 r;
    r[0] = (short)f2bf(a.x); r[1] = (short)f2bf(a.y);
    r[2] = (short)f2bf(a.z); r[3] = (short)f2bf(a.w);
    r[4] = (short)f2bf(b.x); r[5] = (short)f2bf(b.y);
    r[6] = (short)f2bf(b.z); r[7] = (short)f2bf(b.w);
    return r;
}

// argmax over the 16-lane group (first-max-wins) -> lambda. lam9 is LDS.
__device__ __forceinline__ float route_lam(float v, int l15, const float* lam9) {
    int idx = l15;
#pragma unroll
    for (int m = 1; m < 16; m <<= 1) {
        float ov = __shfl_xor(v, m, 16);
        int   oi = __shfl_xor(idx, m, 16);
        bool take = (ov > v) || (ov == v && oi < idx);
        v = take ? ov : v; idx = take ? oi : idx;
    }
    return lam9[idx];
}

// lane (l15,q) holds lam for rows q*4+r after route_lam; every lane needs the
// lam of its own DATA row l15. Intra-wave: 4 shuffles + 3 selects.
__device__ __forceinline__ float lam_bcast(float r0, float r1, float r2, float r3, int l15) {
    const int src = ((l15 >> 2) << 4) + l15;
    float t0 = __shfl(r0, src);
    float t1 = __shfl(r1, src);
    float t2 = __shfl(r2, src);
    float t3 = __shfl(r3, src);
    float lo = (l15 & 1) ? t1 : t0;
    float hi = (l15 & 1) ? t3 : t2;
    return (l15 & 2) ? hi : lo;
}

// ---------------------------------------------------------------------------
// Kernel 1: per-chunk partial KV. PARTIAL=1: coalesced stores to private slot
// [d][e]. PARTIAL=0 (fallback): atomicAdd into shared f32 KV [e][d].
// ---------------------------------------------------------------------------
template<int PARTIAL>
__global__ __launch_bounds__(256, 4) void kv_kernel(
    const float* __restrict__ Kt, const float* __restrict__ Kp,
    const float* __restrict__ V,  const float* __restrict__ lambdas,
    const float* __restrict__ Wk, float* __restrict__ KVout, int nchk)
{
    __shared__ __align__(16) unsigned short kd_s[2][64][LROW];   // [buf][d][s]
    __shared__ float lam9[16];

    const int tid  = threadIdx.x;
    const int lane = tid & 63;
    const int wave = tid >> 6;
    const int l15  = lane & 15;
    const int q    = lane >> 4;
    const int head  = blockIdx.x & (NHEAD - 1);
    const int chunk = blockIdx.x >> 6;
    const size_t hbase = (size_t)head * Sx * HDx;
    const int sck   = Sx / nchk;
    const int ntk   = sck >> 6;
    const int sbase = chunk * sck;
    const int myrow = wave * 16 + l15;

    if (tid < NF) lam9[tid] = lambdas[tid];

    // Router-weight B-frags: B[k=cat-feat][n=router]; cols 9..15 zero.
    bf16x8 wb[4];
#pragma unroll
    for (int h = 0; h < 4; ++h)
#pragma unroll
        for (int j = 0; j < 8; ++j) {
            float w = (l15 < NF) ? Wk[l15 * 128 + h * 32 + q * 8 + j] : 0.f;
            wb[h][j] = (short)f2bf(w);
        }

    f32x4 acc[4];
#pragma unroll
    for (int mt = 0; mt < 4; ++mt) acc[mt] = (f32x4){0.f, 0.f, 0.f, 0.f};

    __syncthreads();   // lam9 visible

    for (int t = 0; t < ntk; ++t) {
        const int s0 = sbase + t * 64;
        // ---- loads, directly in frag layout (64B-coalesced 4-lane clusters) ----
        const float* kt0 = Kt + hbase + (size_t)(s0 + myrow) * HDx + q * 8;
        const float* kp0 = Kp + hbase + (size_t)(s0 + myrow) * HDx + q * 8;
        float4 a0 = *(const float4*)(kt0),      a1 = *(const float4*)(kt0 + 4);
        float4 a2 = *(const float4*)(kt0 + 32), a3 = *(const float4*)(kt0 + 36);
        float4 b0 = *(const float4*)(kp0),      b1 = *(const float4*)(kp0 + 4);
        float4 b2 = *(const float4*)(kp0 + 32), b3 = *(const float4*)(kp0 + 36);
        float vv[16];
#pragma unroll
        for (int h = 0; h < 2; ++h)
#pragma unroll
            for (int j = 0; j < 8; ++j)
                vv[h * 8 + j] = V[hbase + (size_t)(s0 + h * 32 + q * 8 + j) * HDx + wave * 16 + l15];

        bf16x8 af[4];
        af[0] = pack8(a0, a1); af[1] = pack8(a2, a3);
        af[2] = pack8(b0, b1); af[3] = pack8(b2, b3);

        // ---- scores via MFMA ----
        f32x4 sc = (f32x4){0.f, 0.f, 0.f, 0.f};
#pragma unroll
        for (int h = 0; h < 4; ++h)
            sc = __builtin_amdgcn_mfma_f32_16x16x32_bf16(af[h], wb[h], sc, 0, 0, 0);
        float lr0 = route_lam((l15 < NF) ? sc[0] : -3.4e38f, l15, lam9);
        float lr1 = route_lam((l15 < NF) ? sc[1] : -3.4e38f, l15, lam9);
        float lr2 = route_lam((l15 < NF) ? sc[2] : -3.4e38f, l15, lam9);
        float lr3 = route_lam((l15 < NF) ? sc[3] : -3.4e38f, l15, lam9);
        const float lam = lam_bcast(lr0, lr1, lr2, lr3, l15);

        // ---- K_diff, written transposed [d][s] into buffer t&1 ----
#pragma unroll
        for (int h = 0; h < 2; ++h)
#pragma unroll
            for (int j = 0; j < 8; ++j)
                kd_s[t & 1][h * 32 + q * 8 + j][myrow] =
                    f2bf(bf2f((unsigned short)af[h][j]) - lam * bf2f((unsigned short)af[2 + h][j]));

        // V B-frags
        bf16x8 bv[2];
#pragma unroll
        for (int h = 0; h < 2; ++h)
#pragma unroll
            for (int j = 0; j < 8; ++j) bv[h][j] = (short)f2bf(vv[h * 8 + j]);

        __syncthreads();   // kd_s[t&1] writes visible (dbuf -> single barrier/tile)

        // ---- KV MFMA ----
#pragma unroll
        for (int h = 0; h < 2; ++h)
#pragma unroll
            for (int mt = 0; mt < 4; ++mt) {
                bf16x8 ad = *(const bf16x8*)&kd_s[t & 1][mt * 16 + l15][h * 32 + q * 8];
                acc[mt] = __builtin_amdgcn_mfma_f32_16x16x32_bf16(ad, bv[h], acc[mt], 0, 0, 0);
            }
    }

    if (PARTIAL) {
        // private slot, [d][e] layout -> per-(mt,r) 64B-contiguous stores
        float* slot = KVout + (size_t)(head * nchk + chunk) * (HDx * HDx);
#pragma unroll
        for (int mt = 0; mt < 4; ++mt)
#pragma unroll
            for (int r = 0; r < 4; ++r)
                slot[(mt * 16 + q * 4 + r) * 64 + wave * 16 + l15] = acc[mt][r];
    } else {
        float* kvh = KVout + head * (HDx * HDx);   // [e][d]
#pragma unroll
        for (int mt = 0; mt < 4; ++mt)
#pragma unroll
            for (int r = 0; r < 4; ++r)
                atomicAdd(&kvh[(wave * 16 + l15) * 64 + mt * 16 + q * 4 + r], acc[mt][r]);
    }
}

// ---------------------------------------------------------------------------
// Kernel 1b: reduce partials -> bf16 KV in [e][d] (B-frag-readable) order.
// 64 blocks, reads nchk*16KB/head (L2/L3-resident), writes 512KB total.
// ---------------------------------------------------------------------------
__global__ __launch_bounds__(256) void kv_reduce(
    const float* __restrict__ P, unsigned short* __restrict__ KVB, int nchk)
{
    const int head = blockIdx.x;
    const int d  = threadIdx.x & 63;
    const int eq = threadIdx.x >> 6;
    const float* base = P + (size_t)head * nchk * (HDx * HDx) + d * 64 + eq * 16;
    float s[16];
#pragma unroll
    for (int i = 0; i < 16; ++i) s[i] = 0.f;
    for (int p = 0; p < nchk; ++p) {
        const float4* q4 = (const float4*)(base + (size_t)p * (HDx * HDx));
#pragma unroll
        for (int k = 0; k < 4; ++k) {
            float4 v = q4[k];
            s[4 * k + 0] += v.x; s[4 * k + 1] += v.y;
            s[4 * k + 2] += v.z; s[4 * k + 3] += v.w;
        }
    }
    unsigned short* o = KVB + (size_t)head * (HDx * HDx) + d;
#pragma unroll
    for (int i = 0; i < 16; ++i)
        o[(eq * 16 + i) * 64] = f2bf(s[i]);   // KVB[head][e=eq*16+i][d]
}

// ---------------------------------------------------------------------------
// Kernel 2: O[s,e] = sum_d (Qt - lam*Qp)[s,d] * KV[d,e]. Barrier-free loop.
// BF=1: KV preloaded as raw ushort8 frags. BF=0 (fallback): f32 [e][d].
// ---------------------------------------------------------------------------
template<int BF>
__global__ __launch_bounds__(256, 4) void out_kernel(
    const float* __restrict__ Qt, const float* __restrict__ Qp,
    const float* __restrict__ lambdas, const float* __restrict__ Wq,
    const void* __restrict__ KV, float* __restrict__ O)
{
    __shared__ float lam9[16];

    const int tid  = threadIdx.x;
    const int lane = tid & 63;
    const int wave = tid >> 6;
    const int l15  = lane & 15;
    const int q    = lane >> 4;
    const int head  = blockIdx.x & (NHEAD - 1);
    const int chunk = blockIdx.x >> 6;
    const size_t hbase = (size_t)head * Sx * HDx;
    const int s00 = chunk * SCO;
    const int myrow = wave * 16 + l15;

    if (tid < NF) lam9[tid] = lambdas[tid];

    bf16x8 wb[4];
#pragma unroll
    for (int h = 0; h < 4; ++h)
#pragma unroll
        for (int j = 0; j < 8; ++j) {
            float w = (l15 < NF) ? Wq[l15 * 128 + h * 32 + q * 8 + j] : 0.f;
            wb[h][j] = (short)f2bf(w);
        }

    // KV B-frags: B[k=d][n=e]
    bf16x8 bkv[4][2];
    if (BF) {
        const unsigned short* kvb = (const unsigned short*)KV + (size_t)head * (HDx * HDx);
#pragma unroll
        for (int nt = 0; nt < 4; ++nt)
#pragma unroll
            for (int h = 0; h < 2; ++h)
                bkv[nt][h] = *(const bf16x8*)&kvb[(nt * 16 + l15) * 64 + h * 32 + q * 8];
    } else {
        const float* kvh = (const float*)KV + (size_t)head * (HDx * HDx);
#pragma unroll
        for (int nt = 0; nt < 4; ++nt)
#pragma unroll
            for (int h = 0; h < 2; ++h) {
                const float* p = &kvh[(nt * 16 + l15) * 64 + h * 32 + q * 8];
                bkv[nt][h] = pack8(*(const float4*)p, *(const float4*)(p + 4));
            }
    }

    __syncthreads();   // lam9 visible

    for (int t = 0; t < NTO; ++t) {
        const int s0 = s00 + t * 64;
        const float* qt0 = Qt + hbase + (size_t)(s0 + myrow) * HDx + q * 8;
        const float* qp0 = Qp + hbase + (size_t)(s0 + myrow) * HDx + q * 8;
        float4 a0 = *(const float4*)(qt0),      a1 = *(const float4*)(qt0 + 4);
        float4 a2 = *(const float4*)(qt0 + 32), a3 = *(const float4*)(qt0 + 36);
        float4 b0 = *(const float4*)(qp0),      b1 = *(const float4*)(qp0 + 4);
        float4 b2 = *(const float4*)(qp0 + 32), b3 = *(const float4*)(qp0 + 36);

        bf16x8 af[4];
        af[0] = pack8(a0, a1); af[1] = pack8(a2, a3);
        af[2] = pack8(b0, b1); af[3] = pack8(b2, b3);

        f32x4 sc = (f32x4){0.f, 0.f, 0.f, 0.f};
#pragma unroll
        for (int h = 0; h < 4; ++h)
            sc = __builtin_amdgcn_mfma_f32_16x16x32_bf16(af[h], wb[h], sc, 0, 0, 0);
        float lr0 = route_lam((l15 < NF) ? sc[0] : -3.4e38f, l15, lam9);
        float lr1 = route_lam((l15 < NF) ? sc[1] : -3.4e38f, l15, lam9);
        float lr2 = route_lam((l15 < NF) ? sc[2] : -3.4e38f, l15, lam9);
        float lr3 = route_lam((l15 < NF) ? sc[3] : -3.4e38f, l15, lam9);
        const float lam = lam_bcast(lr0, lr1, lr2, lr3, l15);

        bf16x8 ad[2];
#pragma unroll
        for (int h = 0; h < 2; ++h)
#pragma unroll
            for (int j = 0; j < 8; ++j)
                ad[h][j] = (short)f2bf(bf2f((unsigned short)af[h][j])
                                       - lam * bf2f((unsigned short)af[2 + h][j]));

        f32x4 oacc[4];
#pragma unroll
        for (int nt = 0; nt < 4; ++nt) oacc[nt] = (f32x4){0.f, 0.f, 0.f, 0.f};
#pragma unroll
        for (int h = 0; h < 2; ++h)
#pragma unroll
            for (int nt = 0; nt < 4; ++nt)
                oacc[nt] = __builtin_amdgcn_mfma_f32_16x16x32_bf16(ad[h], bkv[nt][h], oacc[nt], 0, 0, 0);

#pragma unroll
        for (int nt = 0; nt < 4; ++nt)
#pragma unroll
            for (int r = 0; r < 4; ++r) {
                const int row = s0 + wave * 16 + q * 4 + r;
                O[hbase + (size_t)row * HDx + nt * 16 + l15] = oacc[nt][r];
            }
    }
}

// ---------------------------------------------------------------------------
extern "C" void kernel_launch(void* const* d_in, const int* in_sizes, int n_in,
                              void* d_out, int out_size, void* d_ws, size_t ws_size,
                              hipStream_t stream) {
    const float* Qt      = (const float*)d_in[0];
    const float* Qp      = (const float*)d_in[1];
    const float* Kt      = (const float*)d_in[2];
    const float* Kp      = (const float*)d_in[3];
    const float* V       = (const float*)d_in[4];
    const float* lambdas = (const float*)d_in[5];
    const float* Wq      = (const float*)d_in[6];
    const float* Wk      = (const float*)d_in[7];
    float* O = (float*)d_out;

    const size_t KVB_RES = 1u << 20;                       // 1 MB reserve for bf16 KV
    const size_t SLOT    = (size_t)HDx * HDx * sizeof(float);  // 16 KB

    // largest nchk in {32,16,8,4,2} whose partials + KVB fit the workspace
    int nchk = 32;
    while (nchk > 2 && ws_size < KVB_RES + (size_t)NHEAD * nchk * SLOT) nchk >>= 1;

    if (ws_size >= KVB_RES + (size_t)NHEAD * nchk * SLOT) {
        unsigned short* KVB = (unsigned short*)d_ws;
        float* KVP = (float*)((char*)d_ws + KVB_RES);
        kv_kernel<1><<<NHEAD * nchk, 256, 0, stream>>>(Kt, Kp, V, lambdas, Wk, KVP, nchk);
        kv_reduce  <<<NHEAD, 256, 0, stream>>>(KVP, KVB, nchk);
        out_kernel<1><<<NHEAD * NCHO, 256, 0, stream>>>(Qt, Qp, lambdas, Wq, KVB, O);
    } else {
        // tiny-workspace fallback: original atomic accumulation path
        float* KVf = (float*)d_ws;   // 1 MB f32 [e][d]
        hipMemsetAsync(d_ws, 0, (size_t)NHEAD * HDx * HDx * sizeof(float), stream);
        kv_kernel<0><<<NHEAD * 16, 256, 0, stream>>>(Kt, Kp, V, lambdas, Wk, KVf, 16);
        out_kernel<0><<<NHEAD * NCHO, 256, 0, stream>>>(Qt, Qp, lambdas, Wq, KVf, O);
    }
}

// Round 3
// 362.193 us; speedup vs baseline: 1.1532x; 1.0338x over previous
//
#include <hip/hip_runtime.h>

// R3: software-pipeline the tile loop. launch_bounds(256,2) frees the VGPR
// budget so cur+nxt register tile sets survive; prefetch of tile t+1 is issued
// at loop-top (sched_barrier-pinned) and its ~900cy latency hides under tile
// t's compute. NCHK/NCHO=16 -> 4 tiles/block. out_kernel barrier-free per
// tile, KV preload amortized over 4 tiles.

#define Sx 4096
#define HDx 64
#define NF 9
#define NHEAD 64
#define NCHK 16            // kv: 1024 blocks, 4 tiles each
#define SCK (Sx / NCHK)
#define NTK (SCK / 64)
#define NCHO 16            // out: 1024 blocks, 4 tiles each
#define SCO (Sx / NCHO)
#define NTO (SCO / 64)
#define LROW 72            // kd_s row stride (bf16 units); 144 B = 16B-aligned

typedef __attribute__((ext_vector_type(8))) short bf16x8;
typedef __attribute__((ext_vector_type(4))) float f32x4;

__device__ __forceinline__ unsigned short f2bf(float f) {
    union { float f; unsigned u; } x; x.f = f;
    unsigned r = x.u + 0x7fffu + ((x.u >> 16) & 1u);   // RNE
    return (unsigned short)(r >> 16);
}
__device__ __forceinline__ float bf2f(unsigned short b) {
    union { unsigned u; float f; } x; x.u = ((unsigned)b) << 16;
    return x.f;
}
__device__ __forceinline__ bf16x8 pack8(float4 a, float4 b) {
    bf16x8 r;
    r[0] = (short)f2bf(a.x); r[1] = (short)f2bf(a.y);
    r[2] = (short)f2bf(a.z); r[3] = (short)f2bf(a.w);
    r[4] = (short)f2bf(b.x); r[5] = (short)f2bf(b.y);
    r[6] = (short)f2bf(b.z); r[7] = (short)f2bf(b.w);
    return r;
}

// argmax over the 16-lane group (first-max-wins) -> lambda. lam9 is LDS.
__device__ __forceinline__ float route_lam(float v, int l15, const float* lam9) {
    int idx = l15;
#pragma unroll
    for (int m = 1; m < 16; m <<= 1) {
        float ov = __shfl_xor(v, m, 16);
        int   oi = __shfl_xor(idx, m, 16);
        bool take = (ov > v) || (ov == v && oi < idx);
        v = take ? ov : v; idx = take ? oi : idx;
    }
    return lam9[idx];
}

// lane (l15,q) holds lam for rows q*4+r after route_lam; every lane needs the
// lam of its own DATA row l15. Intra-wave: 4 shuffles + 3 selects.
__device__ __forceinline__ float lam_bcast(float r0, float r1, float r2, float r3, int l15) {
    const int src = ((l15 >> 2) << 4) + l15;
    float t0 = __shfl(r0, src);
    float t1 = __shfl(r1, src);
    float t2 = __shfl(r2, src);
    float t3 = __shfl(r3, src);
    float lo = (l15 & 1) ? t1 : t0;
    float hi = (l15 & 1) ? t3 : t2;
    return (l15 & 2) ? hi : lo;
}

// one K-tile load set: 8 float4 (Kt,Kp row-frag layout) + 16 scalar V
__device__ __forceinline__ void load_ktile(
    const float* __restrict__ Kt, const float* __restrict__ Kp,
    const float* __restrict__ V, size_t hbase, int s0, int myrow, int q,
    float4 ka[4], float4 kb[4], float vv[16])
{
    const float* kt0 = Kt + hbase + (size_t)(s0 + myrow) * HDx + q * 8;
    const float* kp0 = Kp + hbase + (size_t)(s0 + myrow) * HDx + q * 8;
    ka[0] = *(const float4*)(kt0);      ka[1] = *(const float4*)(kt0 + 4);
    ka[2] = *(const float4*)(kt0 + 32); ka[3] = *(const float4*)(kt0 + 36);
    kb[0] = *(const float4*)(kp0);      kb[1] = *(const float4*)(kp0 + 4);
    kb[2] = *(const float4*)(kp0 + 32); kb[3] = *(const float4*)(kp0 + 36);
#pragma unroll
    for (int h = 0; h < 2; ++h)
#pragma unroll
        for (int j = 0; j < 8; ++j)
            vv[h * 8 + j] = V[hbase + (size_t)(s0 + h * 32 + q * 8 + j) * HDx + myrow];
}

// ---------------------------------------------------------------------------
// Kernel 1: per-chunk partial KV, software-pipelined over NTK tiles.
// ---------------------------------------------------------------------------
template<int PARTIAL>
__global__ __launch_bounds__(256, 2) void kv_kernel(
    const float* __restrict__ Kt, const float* __restrict__ Kp,
    const float* __restrict__ V,  const float* __restrict__ lambdas,
    const float* __restrict__ Wk, float* __restrict__ KVout)
{
    __shared__ __align__(16) unsigned short kd_s[2][64][LROW];   // [buf][d][s]
    __shared__ float lam9[16];

    const int tid  = threadIdx.x;
    const int lane = tid & 63;
    const int wave = tid >> 6;
    const int l15  = lane & 15;
    const int q    = lane >> 4;
    const int head  = blockIdx.x & (NHEAD - 1);
    const int chunk = blockIdx.x >> 6;
    const size_t hbase = (size_t)head * Sx * HDx;
    const int sbase = chunk * SCK;
    const int myrow = wave * 16 + l15;

    if (tid < NF) lam9[tid] = lambdas[tid];

    bf16x8 wb[4];
#pragma unroll
    for (int h = 0; h < 4; ++h)
#pragma unroll
        for (int j = 0; j < 8; ++j) {
            float w = (l15 < NF) ? Wk[l15 * 128 + h * 32 + q * 8 + j] : 0.f;
            wb[h][j] = (short)f2bf(w);
        }

    f32x4 acc[4];
#pragma unroll
    for (int mt = 0; mt < 4; ++mt) acc[mt] = (f32x4){0.f, 0.f, 0.f, 0.f};

    // prologue: tile 0 into cur regs
    float4 ka[4], kb[4]; float vv[16];
    load_ktile(Kt, Kp, V, hbase, sbase, myrow, q, ka, kb, vv);

    __syncthreads();   // lam9 visible

#pragma unroll
    for (int t = 0; t < NTK; ++t) {
        // ---- issue next-tile loads FIRST (latency hides under this tile) ----
        float4 nka[4], nkb[4]; float nvv[16];
        if (t + 1 < NTK)
            load_ktile(Kt, Kp, V, hbase, sbase + (t + 1) * 64, myrow, q, nka, nkb, nvv);
        __builtin_amdgcn_sched_barrier(0);   // pin: don't sink the prefetch

        // ---- scores via MFMA ----
        bf16x8 af[4];
        af[0] = pack8(ka[0], ka[1]); af[1] = pack8(ka[2], ka[3]);
        af[2] = pack8(kb[0], kb[1]); af[3] = pack8(kb[2], kb[3]);
        f32x4 sc = (f32x4){0.f, 0.f, 0.f, 0.f};
#pragma unroll
        for (int h = 0; h < 4; ++h)
            sc = __builtin_amdgcn_mfma_f32_16x16x32_bf16(af[h], wb[h], sc, 0, 0, 0);
        float lr0 = route_lam((l15 < NF) ? sc[0] : -3.4e38f, l15, lam9);
        float lr1 = route_lam((l15 < NF) ? sc[1] : -3.4e38f, l15, lam9);
        float lr2 = route_lam((l15 < NF) ? sc[2] : -3.4e38f, l15, lam9);
        float lr3 = route_lam((l15 < NF) ? sc[3] : -3.4e38f, l15, lam9);
        const float lam = lam_bcast(lr0, lr1, lr2, lr3, l15);

        // ---- K_diff, transposed [d][s] into buffer t&1 ----
#pragma unroll
        for (int h = 0; h < 2; ++h)
#pragma unroll
            for (int j = 0; j < 8; ++j)
                kd_s[t & 1][h * 32 + q * 8 + j][myrow] =
                    f2bf(bf2f((unsigned short)af[h][j]) - lam * bf2f((unsigned short)af[2 + h][j]));

        // V B-frags
        bf16x8 bv[2];
#pragma unroll
        for (int h = 0; h < 2; ++h)
#pragma unroll
            for (int j = 0; j < 8; ++j) bv[h][j] = (short)f2bf(vv[h * 8 + j]);

        __syncthreads();   // kd_s[t&1] visible; prefetch already ~complete

        // ---- KV MFMA ----
#pragma unroll
        for (int h = 0; h < 2; ++h)
#pragma unroll
            for (int mt = 0; mt < 4; ++mt) {
                bf16x8 ad = *(const bf16x8*)&kd_s[t & 1][mt * 16 + l15][h * 32 + q * 8];
                acc[mt] = __builtin_amdgcn_mfma_f32_16x16x32_bf16(ad, bv[h], acc[mt], 0, 0, 0);
            }

        // rotate
        if (t + 1 < NTK) {
#pragma unroll
            for (int i = 0; i < 4; ++i) { ka[i] = nka[i]; kb[i] = nkb[i]; }
#pragma unroll
            for (int j = 0; j < 16; ++j) vv[j] = nvv[j];
        }
    }

    if (PARTIAL) {
        float* slot = KVout + (size_t)(head * NCHK + chunk) * (HDx * HDx);
#pragma unroll
        for (int mt = 0; mt < 4; ++mt)
#pragma unroll
            for (int r = 0; r < 4; ++r)
                slot[(mt * 16 + q * 4 + r) * 64 + wave * 16 + l15] = acc[mt][r];
    } else {
        float* kvh = KVout + head * (HDx * HDx);   // [e][d]
#pragma unroll
        for (int mt = 0; mt < 4; ++mt)
#pragma unroll
            for (int r = 0; r < 4; ++r)
                atomicAdd(&kvh[(wave * 16 + l15) * 64 + mt * 16 + q * 4 + r], acc[mt][r]);
    }
}

// ---------------------------------------------------------------------------
// Kernel 1b: reduce partials -> bf16 KV in [e][d] (B-frag-readable) order.
// ---------------------------------------------------------------------------
__global__ __launch_bounds__(256) void kv_reduce(
    const float* __restrict__ P, unsigned short* __restrict__ KVB)
{
    const int head = blockIdx.x;
    const int d  = threadIdx.x & 63;
    const int eq = threadIdx.x >> 6;
    const float* base = P + (size_t)head * NCHK * (HDx * HDx) + d * 64 + eq * 16;
    float s[16];
#pragma unroll
    for (int i = 0; i < 16; ++i) s[i] = 0.f;
    for (int p = 0; p < NCHK; ++p) {
        const float4* q4 = (const float4*)(base + (size_t)p * (HDx * HDx));
#pragma unroll
        for (int k = 0; k < 4; ++k) {
            float4 v = q4[k];
            s[4 * k + 0] += v.x; s[4 * k + 1] += v.y;
            s[4 * k + 2] += v.z; s[4 * k + 3] += v.w;
        }
    }
    unsigned short* o = KVB + (size_t)head * (HDx * HDx) + d;
#pragma unroll
    for (int i = 0; i < 16; ++i)
        o[(eq * 16 + i) * 64] = f2bf(s[i]);   // KVB[head][e][d]
}

// ---------------------------------------------------------------------------
// Kernel 2: O[s,e] = sum_d (Qt - lam*Qp)[s,d] * KV[d,e].
// Software-pipelined, zero per-tile barriers (one lam9 barrier at start).
// ---------------------------------------------------------------------------
template<int BF>
__global__ __launch_bounds__(256, 2) void out_kernel(
    const float* __restrict__ Qt, const float* __restrict__ Qp,
    const float* __restrict__ lambdas, const float* __restrict__ Wq,
    const void* __restrict__ KV, float* __restrict__ O)
{
    __shared__ float lam9[16];

    const int tid  = threadIdx.x;
    const int lane = tid & 63;
    const int wave = tid >> 6;
    const int l15  = lane & 15;
    const int q    = lane >> 4;
    const int head  = blockIdx.x & (NHEAD - 1);
    const int chunk = blockIdx.x >> 6;
    const size_t hbase = (size_t)head * Sx * HDx;
    const int s00 = chunk * SCO;
    const int myrow = wave * 16 + l15;

    if (tid < NF) lam9[tid] = lambdas[tid];

    bf16x8 wb[4];
#pragma unroll
    for (int h = 0; h < 4; ++h)
#pragma unroll
        for (int j = 0; j < 8; ++j) {
            float w = (l15 < NF) ? Wq[l15 * 128 + h * 32 + q * 8 + j] : 0.f;
            wb[h][j] = (short)f2bf(w);
        }

    // KV B-frags: B[k=d][n=e]
    bf16x8 bkv[4][2];
    if (BF) {
        const unsigned short* kvb = (const unsigned short*)KV + (size_t)head * (HDx * HDx);
#pragma unroll
        for (int nt = 0; nt < 4; ++nt)
#pragma unroll
            for (int h = 0; h < 2; ++h)
                bkv[nt][h] = *(const bf16x8*)&kvb[(nt * 16 + l15) * 64 + h * 32 + q * 8];
    } else {
        const float* kvh = (const float*)KV + (size_t)head * (HDx * HDx);
#pragma unroll
        for (int nt = 0; nt < 4; ++nt)
#pragma unroll
            for (int h = 0; h < 2; ++h) {
                const float* p = &kvh[(nt * 16 + l15) * 64 + h * 32 + q * 8];
                bkv[nt][h] = pack8(*(const float4*)p, *(const float4*)(p + 4));
            }
    }

    // prologue: tile 0
    float4 qa[4], qb[4];
    {
        const float* qt0 = Qt + hbase + (size_t)(s00 + myrow) * HDx + q * 8;
        const float* qp0 = Qp + hbase + (size_t)(s00 + myrow) * HDx + q * 8;
        qa[0] = *(const float4*)(qt0);      qa[1] = *(const float4*)(qt0 + 4);
        qa[2] = *(const float4*)(qt0 + 32); qa[3] = *(const float4*)(qt0 + 36);
        qb[0] = *(const float4*)(qp0);      qb[1] = *(const float4*)(qp0 + 4);
        qb[2] = *(const float4*)(qp0 + 32); qb[3] = *(const float4*)(qp0 + 36);
    }

    __syncthreads();   // lam9 visible (only barrier in the kernel)

#pragma unroll
    for (int t = 0; t < NTO; ++t) {
        // ---- issue next-tile loads first ----
        float4 na[4], nb[4];
        if (t + 1 < NTO) {
            const int s0n = s00 + (t + 1) * 64;
            const float* qt0 = Qt + hbase + (size_t)(s0n + myrow) * HDx + q * 8;
            const float* qp0 = Qp + hbase + (size_t)(s0n + myrow) * HDx + q * 8;
            na[0] = *(const float4*)(qt0);      na[1] = *(const float4*)(qt0 + 4);
            na[2] = *(const float4*)(qt0 + 32); na[3] = *(const float4*)(qt0 + 36);
            nb[0] = *(const float4*)(qp0);      nb[1] = *(const float4*)(qp0 + 4);
            nb[2] = *(const float4*)(qp0 + 32); nb[3] = *(const float4*)(qp0 + 36);
        }
        __builtin_amdgcn_sched_barrier(0);

        bf16x8 af[4];
        af[0] = pack8(qa[0], qa[1]); af[1] = pack8(qa[2], qa[3]);
        af[2] = pack8(qb[0], qb[1]); af[3] = pack8(qb[2], qb[3]);

        f32x4 sc = (f32x4){0.f, 0.f, 0.f, 0.f};
#pragma unroll
        for (int h = 0; h < 4; ++h)
            sc = __builtin_amdgcn_mfma_f32_16x16x32_bf16(af[h], wb[h], sc, 0, 0, 0);
        float lr0 = route_lam((l15 < NF) ? sc[0] : -3.4e38f, l15, lam9);
        float lr1 = route_lam((l15 < NF) ? sc[1] : -3.4e38f, l15, lam9);
        float lr2 = route_lam((l15 < NF) ? sc[2] : -3.4e38f, l15, lam9);
        float lr3 = route_lam((l15 < NF) ? sc[3] : -3.4e38f, l15, lam9);
        const float lam = lam_bcast(lr0, lr1, lr2, lr3, l15);

        bf16x8 ad[2];
#pragma unroll
        for (int h = 0; h < 2; ++h)
#pragma unroll
            for (int j = 0; j < 8; ++j)
                ad[h][j] = (short)f2bf(bf2f((unsigned short)af[h][j])
                                       - lam * bf2f((unsigned short)af[2 + h][j]));

        f32x4 oacc[4];
#pragma unroll
        for (int nt = 0; nt < 4; ++nt) oacc[nt] = (f32x4){0.f, 0.f, 0.f, 0.f};
#pragma unroll
        for (int h = 0; h < 2; ++h)
#pragma unroll
            for (int nt = 0; nt < 4; ++nt)
                oacc[nt] = __builtin_amdgcn_mfma_f32_16x16x32_bf16(ad[h], bkv[nt][h], oacc[nt], 0, 0, 0);

        const int s0 = s00 + t * 64;
#pragma unroll
        for (int nt = 0; nt < 4; ++nt)
#pragma unroll
            for (int r = 0; r < 4; ++r) {
                const int row = s0 + wave * 16 + q * 4 + r;
                O[hbase + (size_t)row * HDx + nt * 16 + l15] = oacc[nt][r];
            }

        if (t + 1 < NTO) {
#pragma unroll
            for (int i = 0; i < 4; ++i) { qa[i] = na[i]; qb[i] = nb[i]; }
        }
    }
}

// ---------------------------------------------------------------------------
extern "C" void kernel_launch(void* const* d_in, const int* in_sizes, int n_in,
                              void* d_out, int out_size, void* d_ws, size_t ws_size,
                              hipStream_t stream) {
    const float* Qt      = (const float*)d_in[0];
    const float* Qp      = (const float*)d_in[1];
    const float* Kt      = (const float*)d_in[2];
    const float* Kp      = (const float*)d_in[3];
    const float* V       = (const float*)d_in[4];
    const float* lambdas = (const float*)d_in[5];
    const float* Wq      = (const float*)d_in[6];
    const float* Wk      = (const float*)d_in[7];
    float* O = (float*)d_out;

    const size_t KVB_RES = 1u << 20;                          // bf16 KV reserve
    const size_t SLOT    = (size_t)HDx * HDx * sizeof(float); // 16 KB
    const size_t NEED    = KVB_RES + (size_t)NHEAD * NCHK * SLOT;  // 17 MB

    if (ws_size >= NEED) {
        unsigned short* KVB = (unsigned short*)d_ws;
        float* KVP = (float*)((char*)d_ws + KVB_RES);
        kv_kernel<1><<<NHEAD * NCHK, 256, 0, stream>>>(Kt, Kp, V, lambdas, Wk, KVP);
        kv_reduce  <<<NHEAD, 256, 0, stream>>>(KVP, KVB);
        out_kernel<1><<<NHEAD * NCHO, 256, 0, stream>>>(Qt, Qp, lambdas, Wq, KVB, O);
    } else {
        // tiny-workspace fallback: atomic accumulation path
        float* KVf = (float*)d_ws;   // 1 MB f32 [e][d]
        hipMemsetAsync(d_ws, 0, (size_t)NHEAD * HDx * HDx * sizeof(float), stream);
        kv_kernel<0><<<NHEAD * NCHK, 256, 0, stream>>>(Kt, Kp, V, lambdas, Wk, KVf);
        out_kernel<0><<<NHEAD * NCHO, 256, 0, stream>>>(Qt, Qp, lambdas, Wq, KVf, O);
    }
}